// Round 12
// baseline (149.815 us; speedup 1.0000x reference)
//
#include <hip/hip_runtime.h>
#include <math.h>

#define DDIM 2048
#define NEXP 64
#define BM 32            // (mono fallback tile)
#define BK 64
#define THETA 3e-5f
#define MAXFLAG 16383
#define FLAGREGION 65536
#define WPACKB (64 * 4 * 2 * 1024)   // 512 KB packed W frags

typedef __attribute__((ext_vector_type(8))) short bf16x8;
typedef __attribute__((ext_vector_type(4))) float f32x4;

union B16 { uint4 u; bf16x8 v; };

// RNE f32->bf16 pair pack (offline W split)
__device__ inline unsigned pkbf(float a, float b, float& fa, float& fb) {
    unsigned ba = __float_as_uint(a), bb = __float_as_uint(b);
    unsigned ra = (ba + 0x7fffu + ((ba >> 16) & 1u)) & 0xffff0000u;
    unsigned rb = (bb + 0x7fffu + ((bb >> 16) & 1u)) & 0xffff0000u;
    fa = __uint_as_float(ra); fb = __uint_as_float(rb);
    return (ra >> 16) | rb;
}

// trunc-pack: dst = [bf16t(b) | bf16t(a)] via one v_perm
__device__ inline unsigned pkh(unsigned a, unsigned b) {
    return __builtin_amdgcn_perm(b, a, 0x07060302u);
}
// low-part pack: xl = x - trunc16(x), trunc-packed (exact sub; bf16 rounding
// of xl only -> score err ~2.5e-6 << THETA)
__device__ inline unsigned pkl(unsigned a, unsigned b) {
    const float fa = __uint_as_float(a) - __uint_as_float(a & 0xffff0000u);
    const float fb = __uint_as_float(b) - __uint_as_float(b & 0xffff0000u);
    return pkh(__float_as_uint(fa), __float_as_uint(fb));
}

// ---------------------------------------------------------------------------
// Kernel 0: pack W[64][2048] f32 into MFMA B-fragment order, RNE bf16 split.
// Wp byte layout: ((ks*4 + et)*2 + hl)*1024 + lane*16 ; frag elem j is
// W[et*16 + (lane&15)][32*ks + 8*(lane>>4) + j]. 512 KB, L2-resident.
// ---------------------------------------------------------------------------
__global__ void w_pack(const float* __restrict__ W, ushort* __restrict__ Wp) {
    const int gid = blockIdx.x * 256 + threadIdx.x;   // 16384 = 64ks*4et*64ln
    const int ln = gid & 63, et = (gid >> 6) & 3, ks = gid >> 8;
    const float* src = W + (size_t)(et * 16 + (ln & 15)) * DDIM + 32 * ks + 8 * (ln >> 4);
    const float4 f0 = *(const float4*)(src);
    const float4 f1 = *(const float4*)(src + 4);
    uint4 H, L; float h0, h1, h2, h3, h4, h5, h6, h7, d;
    H.x = pkbf(f0.x, f0.y, h0, h1);
    H.y = pkbf(f0.z, f0.w, h2, h3);
    H.z = pkbf(f1.x, f1.y, h4, h5);
    H.w = pkbf(f1.z, f1.w, h6, h7);
    L.x = pkbf(f0.x - h0, f0.y - h1, d, d);
    L.y = pkbf(f0.z - h2, f0.w - h3, d, d);
    L.z = pkbf(f1.x - h4, f1.y - h5, d, d);
    L.w = pkbf(f1.z - h6, f1.w - h7, d, d);
    const size_t hb = ((size_t)(ks * 4 + et) * 2 + 0) * 512 + ln * 8;  // ushort units
    const size_t lb = ((size_t)(ks * 4 + et) * 2 + 1) * 512 + ln * 8;
    *(uint4*)(Wp + hb) = H;
    *(uint4*)(Wp + lb) = L;
}

// ---------------------------------------------------------------------------
// Kernel 1: counted-vmcnt streaming MFMA gate, DEPTH-4 pipeline.
// R11 (depth-2, vmcnt(4)) was still latency-bound: retire distance 2 steps
// (~150cyc) << L2/HBM latency (500-900cyc) -> VALUBusy 20%, 107us.
// Now: uniform [X_k,W_k] issue; steady outstanding after issue = 16;
// s_waitcnt vmcnt(12) at step k retires exactly step-k's 4 loads (issued
// 4 steps earlier). Tolerance = 4 steps x ~80cyc x 4 waves/SIMD ~ 1300cyc.
// Buffers: 4x(Xa,Xb,Wh,Wl) = 16 uint4. Tail clamps to k=63 (benign dups),
// single vmcnt(0) before register reuse in epilogue.
// ---------------------------------------------------------------------------
__launch_bounds__(256, 2)
__global__ void gate_main(const float* __restrict__ x, const ushort* __restrict__ Wp,
                          const float* __restrict__ gb, float* __restrict__ out,
                          int* __restrict__ wsc, int M) {
    __shared__ float sc[16][NEXP + 4];   // 4.3 KB

    const int tid = threadIdx.x;
    const int lane = tid & 63;
    const int w = tid >> 6;
    const int wu = __builtin_amdgcn_readfirstlane(w);
    const int tok0 = blockIdx.x * 16;

    const float* xbase = x + (size_t)tok0 * DDIM;      // SGPR base
    const ushort* wbase = Wp + (size_t)wu * 1024;      // +wu*2048 B, SGPR
    const unsigned xoffb = (unsigned)(((lane & 15) * 8192) + ((lane >> 4) * 32));
    const unsigned woffb = (unsigned)(lane * 16);

    f32x4 acc = (f32x4){0.f, 0.f, 0.f, 0.f};

    uint4 X0a, X0b, X1a, X1b, X2a, X2b, X3a, X3b;
    uint4 Wh0, Wl0, Wh1, Wl1, Wh2, Wl2, Wh3, Wl3;

#define ISSUE_X(XA, XB, KST)                                                  \
    do {                                                                      \
        const unsigned _ox = xoffb + (unsigned)(KST) * 128u;                  \
        asm volatile("global_load_dwordx4 %0, %1, %2 offset:0"                \
                     : "=&v"(XA) : "v"(_ox), "s"(xbase));                     \
        asm volatile("global_load_dwordx4 %0, %1, %2 offset:16"               \
                     : "=&v"(XB) : "v"(_ox), "s"(xbase));                     \
    } while (0)

#define ISSUE_W(WH, WL, KST)                                                  \
    do {                                                                      \
        const unsigned _ow = woffb + (unsigned)(KST) * 8192u;                 \
        asm volatile("global_load_dwordx4 %0, %1, %2 offset:0"                \
                     : "=&v"(WH) : "v"(_ow), "s"(wbase));                     \
        asm volatile("global_load_dwordx4 %0, %1, %2 offset:1024"             \
                     : "=&v"(WL) : "v"(_ow), "s"(wbase));                     \
    } while (0)

#define COMPUTE(XA, XB, WH, WL)                                               \
    do {                                                                      \
        B16 ah, al, bh, bl;                                                   \
        ah.u.x = pkh(XA.x, XA.y); ah.u.y = pkh(XA.z, XA.w);                   \
        ah.u.z = pkh(XB.x, XB.y); ah.u.w = pkh(XB.z, XB.w);                   \
        al.u.x = pkl(XA.x, XA.y); al.u.y = pkl(XA.z, XA.w);                   \
        al.u.z = pkl(XB.x, XB.y); al.u.w = pkl(XB.z, XB.w);                   \
        bh.u = WH; bl.u = WL;                                                 \
        acc = __builtin_amdgcn_mfma_f32_16x16x32_bf16(ah.v, bh.v, acc, 0, 0, 0); \
        acc = __builtin_amdgcn_mfma_f32_16x16x32_bf16(ah.v, bl.v, acc, 0, 0, 0); \
        acc = __builtin_amdgcn_mfma_f32_16x16x32_bf16(al.v, bh.v, acc, 0, 0, 0); \
    } while (0)

#define STEP(K, XA, XB, WH, WL)                                               \
    do {                                                                      \
        asm volatile("s_waitcnt vmcnt(12)" ::: "memory");                     \
        __builtin_amdgcn_sched_barrier(0);                                    \
        COMPUTE(XA, XB, WH, WL);                                              \
        const int _k4 = (K) + 4 > 63 ? 63 : (K) + 4;                          \
        ISSUE_X(XA, XB, _k4);                                                 \
        ISSUE_W(WH, WL, _k4);                                                 \
    } while (0)

    // prologue: [X_k, W_k] for k=0..3, uniform with steady-state issue order
    ISSUE_X(X0a, X0b, 0); ISSUE_W(Wh0, Wl0, 0);
    ISSUE_X(X1a, X1b, 1); ISSUE_W(Wh1, Wl1, 1);
    ISSUE_X(X2a, X2b, 2); ISSUE_W(Wh2, Wl2, 2);
    ISSUE_X(X3a, X3b, 3); ISSUE_W(Wh3, Wl3, 3);

    for (int k0 = 0; k0 < 64; k0 += 4) {
        STEP(k0 + 0, X0a, X0b, Wh0, Wl0);
        STEP(k0 + 1, X1a, X1b, Wh1, Wl1);
        STEP(k0 + 2, X2a, X2b, Wh2, Wl2);
        STEP(k0 + 3, X3a, X3b, Wh3, Wl3);
    }
    asm volatile("s_waitcnt vmcnt(0)" ::: "memory");   // drain tail dups before
    __builtin_amdgcn_sched_barrier(0);                 // registers are reused

#undef STEP
#undef COMPUTE
#undef ISSUE_W
#undef ISSUE_X

    // ---- epilogue: logit table, then top-7 (4 tokens per wave) ----
#pragma unroll
    for (int rg = 0; rg < 4; ++rg)
        sc[(lane >> 4) * 4 + rg][16 * wu + (lane & 15)] = acc[rg];  // C-map (R7/R8-verified)
    __syncthreads();

    const float gbl = gb[lane];
    for (int tt = 4 * w; tt < 4 * w + 4; ++tt) {
        const float lg = sc[tt][lane];
        const float sg = 1.f / (1.f + expf(-lg));
        float cur = sg + gbl;

        float vals[7]; int idxs[7]; float us[7];
#pragma unroll
        for (int p = 0; p < 7; ++p) {
            float v = cur; int id = lane;
#pragma unroll
            for (int o = 32; o > 0; o >>= 1) {   // butterfly argmax, tie->low idx
                const float ov = __shfl_xor(v, o, 64);
                const int oid = __shfl_xor(id, o, 64);
                const bool take = (ov > v) || (ov == v && oid < id);
                v = take ? ov : v;
                id = take ? oid : id;
            }
            vals[p] = v; idxs[p] = id;
            us[p] = __shfl(sg, id, 64);
            if (lane == id) cur = -1e30f;
        }

        if (lane == 0) {
            const int t = tok0 + tt;
            bool flag = false;
#pragma unroll
            for (int p = 0; p < 6; ++p) flag = flag || (vals[p] - vals[p + 1] < THETA);
            float sum = 0.f;
#pragma unroll
            for (int p = 0; p < 6; ++p) sum += us[p];
#pragma unroll
            for (int p = 0; p < 6; ++p)
                out[(size_t)t * 6 + p] = us[p] / sum * 2.5f;
            float* oi = out + (size_t)M * 6 + (size_t)t * 8;
            oi[0] = 0.f; oi[1] = 1.f;
#pragma unroll
            for (int p = 0; p < 6; ++p) oi[2 + p] = (float)(idxs[p] + 2);
            if (flag) {
                const int pos = atomicAdd(wsc, 1);
                if (pos < MAXFLAG) wsc[1 + pos] = t;
            }
        }
    }
}

// ---------------------------------------------------------------------------
// Kernel 2: f64 refine of flagged tokens (exact ordering). Unchanged.
// ---------------------------------------------------------------------------
__launch_bounds__(256, 2)
__global__ void gate_refine(const float* __restrict__ x, const float* __restrict__ W,
                            const float* __restrict__ gb, float* __restrict__ out,
                            const int* __restrict__ wsc, int M) {
    __shared__ double lg[NEXP];
    int cnt = wsc[0];
    if (cnt > MAXFLAG) cnt = MAXFLAG;
    const int wv = threadIdx.x >> 6;
    const int lane = threadIdx.x & 63;

    for (int i = blockIdx.x; i < cnt; i += gridDim.x) {
        const int t = wsc[1 + i];
        const float* xr = x + (size_t)t * DDIM;
        for (int ee = 0; ee < 16; ++ee) {
            const int e = wv * 16 + ee;
            const float* wr = W + (size_t)e * DDIM;
            double a0 = 0, a1 = 0, a2 = 0, a3 = 0;
#pragma unroll
            for (int it = 0; it < DDIM / 256; ++it) {
                const float4 xv = *(const float4*)(xr + it * 256 + lane * 4);
                const float4 wvv = *(const float4*)(wr + it * 256 + lane * 4);
                a0 = fma((double)xv.x, (double)wvv.x, a0);
                a1 = fma((double)xv.y, (double)wvv.y, a1);
                a2 = fma((double)xv.z, (double)wvv.z, a2);
                a3 = fma((double)xv.w, (double)wvv.w, a3);
            }
            double sd = (a0 + a1) + (a2 + a3);
#pragma unroll
            for (int o = 32; o > 0; o >>= 1) sd += __shfl_down(sd, o, 64);
            if (lane == 0) lg[e] = sd;
        }
        __syncthreads();
        if (threadIdx.x < NEXP) {
            const double l = lg[threadIdx.x];
            lg[threadIdx.x] = 1.0 / (1.0 + exp(-l)) + (double)gb[threadIdx.x];
        }
        __syncthreads();
        if (threadIdx.x == 0) {
            double val[7]; int idx[7];
#pragma unroll
            for (int p = 0; p < 7; ++p) { val[p] = -1e30; idx[p] = 0; }
            for (int e = 0; e < NEXP; ++e) {
                double v = lg[e]; int id = e;
#pragma unroll
                for (int p = 0; p < 7; ++p) {
                    const bool gt = v > val[p];
                    const double ov = val[p]; const int oi2 = idx[p];
                    val[p] = gt ? v : ov; idx[p] = gt ? id : oi2;
                    v = gt ? ov : v;      id = gt ? oi2 : id;
                }
            }
            double s6[6], sum = 0.0;
#pragma unroll
            for (int p = 0; p < 6; ++p) { s6[p] = val[p] - (double)gb[idx[p]]; sum += s6[p]; }
#pragma unroll
            for (int p = 0; p < 6; ++p)
                out[(size_t)t * 6 + p] = (float)(s6[p] / sum * 2.5);
            float* oi = out + (size_t)M * 6 + (size_t)t * 8;
            oi[0] = 0.f; oi[1] = 1.f;
#pragma unroll
            for (int p = 0; p < 6; ++p) oi[2 + p] = (float)(idx[p] + 2);
        }
        __syncthreads();
    }
}

// ---------------------------------------------------------------------------
// Fallback: monolithic vector kernel (used only if ws too small)
// ---------------------------------------------------------------------------
__launch_bounds__(256, 2)
__global__ void gate_mono(const float* __restrict__ x, const float* __restrict__ W,
                          const float* __restrict__ gb, float* __restrict__ out,
                          int* __restrict__ wsc, int M) {
    __shared__ __align__(16) float xs[BK * BM];
    __shared__ __align__(16) float wsh[BK * NEXP];

    const int tid = threadIdx.x;
    const int tg = tid & 15;
    const int eg = tid >> 4;
    const int tok0 = blockIdx.x * BM;
    const int sr = tid >> 3;
    const int sq = tid & 7;
    const float* xsrc  = x + (size_t)(tok0 + sr) * DDIM + 4 * sq;
    const float* wsrc0 = W + (size_t)sr * DDIM + 4 * sq;
    const float* wsrc1 = W + (size_t)(sr + 32) * DDIM + 4 * sq;

    int xoff[16], woff[16];
#pragma unroll
    for (int c = 0; c < 16; ++c) {
        xoff[c] = c * (BM * 4) + 8 * (tg ^ c);
        woff[c] = c * (NEXP * 4) + 16 * (eg ^ c);
    }
    float acc[2][4];
#pragma unroll
    for (int i = 0; i < 2; ++i)
#pragma unroll
        for (int j = 0; j < 4; ++j) acc[i][j] = 0.f;

    float4 px0 = *(const float4*)(xsrc);
    float4 px1 = *(const float4*)(xsrc + 32);
    float4 pw00 = *(const float4*)(wsrc0);
    float4 pw01 = *(const float4*)(wsrc0 + 32);
    float4 pw10 = *(const float4*)(wsrc1);
    float4 pw11 = *(const float4*)(wsrc1 + 32);

    for (int ch = 0; ch < DDIM / BK; ++ch) {
        __syncthreads();
#pragma unroll
        for (int m = 0; m < 4; ++m) {
            const int kkA = 4 * sq + m;
            const int kkB = kkA + 32;
            xs[kkA * BM + ((sr & 1) + 2 * ((sr >> 1) ^ (kkA & 15)))] = ((const float*)&px0)[m];
            xs[kkB * BM + ((sr & 1) + 2 * ((sr >> 1) ^ (kkB & 15)))] = ((const float*)&px1)[m];
            wsh[kkA * NEXP + ((sr & 3) + 4 * ((sr >> 2) ^ (kkA & 15)))] = ((const float*)&pw00)[m];
            wsh[kkB * NEXP + ((sr & 3) + 4 * ((sr >> 2) ^ (kkB & 15)))] = ((const float*)&pw01)[m];
            wsh[kkA * NEXP + (((sr + 32) & 3) + 4 * (((sr + 32) >> 2) ^ (kkA & 15)))] = ((const float*)&pw10)[m];
            wsh[kkB * NEXP + (((sr + 32) & 3) + 4 * (((sr + 32) >> 2) ^ (kkB & 15)))] = ((const float*)&pw11)[m];
        }
        __syncthreads();
        if (ch + 1 < DDIM / BK) {
            const int k0 = (ch + 1) * BK;
            px0 = *(const float4*)(xsrc + k0);
            px1 = *(const float4*)(xsrc + k0 + 32);
            pw00 = *(const float4*)(wsrc0 + k0);
            pw01 = *(const float4*)(wsrc0 + k0 + 32);
            pw10 = *(const float4*)(wsrc1 + k0);
            pw11 = *(const float4*)(wsrc1 + k0 + 32);
        }
        const char* xb = (const char*)xs;
        const char* wb = (const char*)wsh;
#pragma unroll
        for (int rep = 0; rep < 4; ++rep) {
#pragma unroll
            for (int c = 0; c < 16; ++c) {
                const float2 xv = *(const float2*)(xb + rep * (16 * BM * 4) + xoff[c]);
                const float4 wv = *(const float4*)(wb + rep * (16 * NEXP * 4) + woff[c]);
                acc[0][0] = fmaf(xv.x, wv.x, acc[0][0]);
                acc[0][1] = fmaf(xv.x, wv.y, acc[0][1]);
                acc[0][2] = fmaf(xv.x, wv.z, acc[0][2]);
                acc[0][3] = fmaf(xv.x, wv.w, acc[0][3]);
                acc[1][0] = fmaf(xv.y, wv.x, acc[1][0]);
                acc[1][1] = fmaf(xv.y, wv.y, acc[1][1]);
                acc[1][2] = fmaf(xv.y, wv.z, acc[1][2]);
                acc[1][3] = fmaf(xv.y, wv.w, acc[1][3]);
            }
        }
    }

    __syncthreads();
    float* sc = wsh;
#pragma unroll
    for (int i = 0; i < 2; ++i)
#pragma unroll
        for (int j = 0; j < 4; ++j)
            sc[(2 * tg + i) * 68 + (4 * eg + j)] = acc[i][j];
    __syncthreads();

    if (tid < BM) {
        const int t = tok0 + tid;
        float val[7]; int idx[7];
#pragma unroll
        for (int p = 0; p < 7; ++p) { val[p] = -1e30f; idx[p] = 0; }
        for (int e = 0; e < NEXP; ++e) {
            const float l = sc[tid * 68 + e];
            const float sg = 1.f / (1.f + expf(-l));
            float v = sg + gb[e];
            int id = e;
#pragma unroll
            for (int p = 0; p < 7; ++p) {
                const bool gt = v > val[p];
                const float ov = val[p]; const int oi = idx[p];
                val[p] = gt ? v : ov;  idx[p] = gt ? id : oi;
                v = gt ? ov : v;       id = gt ? oi : id;
            }
        }
        bool flag = false;
#pragma unroll
        for (int p = 0; p < 6; ++p) flag = flag || (val[p] - val[p + 1] < THETA);

        float s6[6]; float sum = 0.f;
#pragma unroll
        for (int p = 0; p < 6; ++p) {
            const float l = sc[tid * 68 + idx[p]];
            s6[p] = 1.f / (1.f + expf(-l));
            sum += s6[p];
        }
#pragma unroll
        for (int p = 0; p < 6; ++p)
            out[(size_t)t * 6 + p] = s6[p] / sum * 2.5f;

        float* oi = out + (size_t)M * 6 + (size_t)t * 8;
        oi[0] = 0.f; oi[1] = 1.f;
#pragma unroll
        for (int p = 0; p < 6; ++p) oi[2 + p] = (float)(idx[p] + 2);

        if (flag && wsc) {
            const int pos = atomicAdd(wsc, 1);
            if (pos < MAXFLAG) wsc[1 + pos] = t;
        }
    }
}

extern "C" void kernel_launch(void* const* d_in, const int* in_sizes, int n_in,
                              void* d_out, int out_size, void* d_ws, size_t ws_size,
                              hipStream_t stream) {
    const float* x = (const float*)d_in[0];
    const float* W = (const float*)d_in[1];
    const float* gb = (const float*)d_in[2];
    float* out = (float*)d_out;
    const int M = in_sizes[0] / DDIM;   // 16384

    // ws layout: [flags 64KB | Wp 512KB]
    const size_t need = (size_t)FLAGREGION + (size_t)WPACKB;

    if (ws_size >= need && (M % 16) == 0) {
        int* wsc = (int*)d_ws;
        ushort* Wp = (ushort*)((char*)d_ws + FLAGREGION);
        hipMemsetAsync(d_ws, 0, sizeof(int), stream);
        hipLaunchKernelGGL(w_pack, dim3(64), dim3(256), 0, stream, W, Wp);
        hipLaunchKernelGGL(gate_main, dim3(M / 16), dim3(256), 0, stream,
                           x, Wp, gb, out, wsc, M);
        hipLaunchKernelGGL(gate_refine, dim3(256), dim3(256), 0, stream,
                           x, W, gb, out, wsc, M);
    } else {
        const bool refine_ok = ws_size >= (size_t)(1 + MAXFLAG) * sizeof(int);
        int* wsc = refine_ok ? (int*)d_ws : (int*)nullptr;
        if (refine_ok) hipMemsetAsync(d_ws, 0, sizeof(int), stream);
        hipLaunchKernelGGL(gate_mono, dim3(M / BM), dim3(256), 0, stream,
                           x, W, gb, out, wsc, M);
        if (refine_ok)
            hipLaunchKernelGGL(gate_refine, dim3(256), dim3(256), 0, stream,
                               x, W, gb, out, wsc, M);
    }
}

// Round 13
// 123.732 us; speedup vs baseline: 1.2108x; 1.2108x over previous
//
#include <hip/hip_runtime.h>
#include <math.h>

#define DDIM 2048
#define NEXP 64
#define BM 32            // (mono fallback tile)
#define BK 64
#define THETA 3e-5f
#define MAXFLAG 16383
#define FLAGREGION 65536
#define WPACKB (64 * 4 * 2 * 1024)   // 512 KB packed W frags

typedef __attribute__((ext_vector_type(8))) short bf16x8;
typedef __attribute__((ext_vector_type(4))) float f32x4;

union B16 { uint4 u; bf16x8 v; };

// RNE f32->bf16 pair pack (offline W split)
__device__ inline unsigned pkbf(float a, float b, float& fa, float& fb) {
    unsigned ba = __float_as_uint(a), bb = __float_as_uint(b);
    unsigned ra = (ba + 0x7fffu + ((ba >> 16) & 1u)) & 0xffff0000u;
    unsigned rb = (bb + 0x7fffu + ((bb >> 16) & 1u)) & 0xffff0000u;
    fa = __uint_as_float(ra); fb = __uint_as_float(rb);
    return (ra >> 16) | rb;
}

// trunc-pack: dst = [bf16t(b) | bf16t(a)] via one v_perm
__device__ inline unsigned pkh(unsigned a, unsigned b) {
    return __builtin_amdgcn_perm(b, a, 0x07060302u);
}
// low-part pack: xl = x - trunc16(x), trunc-packed
__device__ inline unsigned pkl(unsigned a, unsigned b) {
    const float fa = __uint_as_float(a) - __uint_as_float(a & 0xffff0000u);
    const float fb = __uint_as_float(b) - __uint_as_float(b & 0xffff0000u);
    return pkh(__float_as_uint(fa), __float_as_uint(fb));
}

// ---------------------------------------------------------------------------
// Kernel 0: pack W[64][2048] f32 into MFMA B-fragment order, RNE bf16 split.
// Wp byte layout: ((ks*4 + et)*2 + hl)*1024 + lane*16. 512 KB, L2-resident.
// ---------------------------------------------------------------------------
__global__ void w_pack(const float* __restrict__ W, ushort* __restrict__ Wp) {
    const int gid = blockIdx.x * 256 + threadIdx.x;   // 16384 = 64ks*4et*64ln
    const int ln = gid & 63, et = (gid >> 6) & 3, ks = gid >> 8;
    const float* src = W + (size_t)(et * 16 + (ln & 15)) * DDIM + 32 * ks + 8 * (ln >> 4);
    const float4 f0 = *(const float4*)(src);
    const float4 f1 = *(const float4*)(src + 4);
    uint4 H, L; float h0, h1, h2, h3, h4, h5, h6, h7, d;
    H.x = pkbf(f0.x, f0.y, h0, h1);
    H.y = pkbf(f0.z, f0.w, h2, h3);
    H.z = pkbf(f1.x, f1.y, h4, h5);
    H.w = pkbf(f1.z, f1.w, h6, h7);
    L.x = pkbf(f0.x - h0, f0.y - h1, d, d);
    L.y = pkbf(f0.z - h2, f0.w - h3, d, d);
    L.z = pkbf(f1.x - h4, f1.y - h5, d, d);
    L.w = pkbf(f1.z - h6, f1.w - h7, d, d);
    const size_t hb = ((size_t)(ks * 4 + et) * 2 + 0) * 512 + ln * 8;  // ushort units
    const size_t lb = ((size_t)(ks * 4 + et) * 2 + 1) * 512 + ln * 8;
    *(uint4*)(Wp + hb) = H;
    *(uint4*)(Wp + lb) = L;
}

// ---------------------------------------------------------------------------
// Kernel 1: coalesced-gll streaming MFMA gate, per-wave PRIVATE LDS staging.
// Block = 32 tokens x 4 waves; wave (tg,eh) = 16 tokens x 32 experts.
// Grid 512 = 2 blk/CU. Per kstep: 2 global_load_lds (x, contiguous 128B/row
// runs, source pre-swizzled 16B-XOR) + 4 asm W loads (1KB coalesced, Wp).
// Private staging -> vmcnt alone syncs gll->ds_read: ZERO in-loop barriers.
// Uniform issue [W(k+1), x(k+3)] -> uniform s_waitcnt vmcnt(2) per kstep
// (retires x(k+1), W(k)). Tail = clamped benign dups; vmcnt(0) at end.
// R12 falsified depth-scaling: stall was 16-scattered-line x loads; now every
// global access is contiguous.
// ---------------------------------------------------------------------------
__launch_bounds__(256, 2)
__global__ void gate_main(const float* __restrict__ x, const ushort* __restrict__ Wp,
                          const float* __restrict__ gb, float* __restrict__ out,
                          int* __restrict__ wsc, int M) {
    __shared__ __align__(16) char stage[4][8192];   // per-wave 4x2KB ring
    __shared__ float sc[32][NEXP + 4];              // 8.7 KB logit table

    const int tid = threadIdx.x;
    const int lane = tid & 63;
    const int w = tid >> 6;
    const int wu = __builtin_amdgcn_readfirstlane(w);
    const int tg = wu >> 1, eh = wu & 1;
    const int tok0 = blockIdx.x * 32;
    const int tokw = tok0 + tg * 16;

    // x gll source (per lane, 2 instrs): instr i covers rows 8i..8i+7.
    // LDS slot u (16B) of row t holds source chunk u ^ (t&7); here per-lane:
    // row-in-group lr = lane>>3 (== t&7), slot uc = (lane&7) ^ lr.
    const int lr = lane >> 3;
    const int uc = (lane & 7) ^ lr;
    const float* gp0 = x + (size_t)(tokw + lr) * DDIM + uc * 4;
    const float* gp1 = x + (size_t)(tokw + 8 + lr) * DDIM + uc * 4;

    // frag-read offsets (match store swizzle): t=lane&15, s=lane>>4, m=t&7
    const int tA = lane & 15, sA = lane >> 4, mA = tA & 7;
    const int fo0 = tA * 128 + (((2 * sA) ^ mA) << 4);
    const int fo1 = tA * 128 + (((2 * sA + 1) ^ mA) << 4);
    const char* mybase = &stage[wu][0];

    const unsigned wofs = (unsigned)(lane * 16 + eh * 4096);
    const ushort* wbase = Wp;   // SGPR base

    f32x4 acc0 = (f32x4){0.f, 0.f, 0.f, 0.f};
    f32x4 acc1 = (f32x4){0.f, 0.f, 0.f, 0.f};

    uint4 A0, A1, A2, A3, B0, B1, B2, B3;   // W sets: {bh(et0),bl(et0),bh(et1),bl(et1)}

#define ISSUE_W(S0, S1, S2, S3, KST)                                          \
    do {                                                                      \
        const int _kc = (KST) > 63 ? 63 : (KST);                              \
        const unsigned _ow = wofs + (unsigned)_kc * 8192u;                    \
        asm volatile("global_load_dwordx4 %0, %1, %2 offset:0"                \
                     : "=&v"(S0) : "v"(_ow), "s"(wbase));                     \
        asm volatile("global_load_dwordx4 %0, %1, %2 offset:1024"             \
                     : "=&v"(S1) : "v"(_ow), "s"(wbase));                     \
        asm volatile("global_load_dwordx4 %0, %1, %2 offset:2048"             \
                     : "=&v"(S2) : "v"(_ow), "s"(wbase));                     \
        asm volatile("global_load_dwordx4 %0, %1, %2 offset:3072"             \
                     : "=&v"(S3) : "v"(_ow), "s"(wbase));                     \
    } while (0)

#define ISSUE_X(KST)                                                          \
    do {                                                                      \
        const int _kc = (KST) > 63 ? 63 : (KST);                              \
        char* _d = &stage[wu][((KST) & 3) * 2048];                            \
        __builtin_amdgcn_global_load_lds((const unsigned*)(gp0 + _kc * 32),   \
                                         (unsigned*)_d, 16, 0, 0);            \
        __builtin_amdgcn_global_load_lds((const unsigned*)(gp1 + _kc * 32),   \
                                         (unsigned*)(_d + 1024), 16, 0, 0);   \
    } while (0)

#define BODY(K, WS0, WS1, WS2, WS3, WT0, WT1, WT2, WT3)                       \
    do {                                                                      \
        asm volatile("s_waitcnt vmcnt(2)" ::: "memory");                      \
        __builtin_amdgcn_sched_barrier(0);                                    \
        const char* _bb = mybase + ((K) & 3) * 2048;                          \
        const uint4 Ra = *(const uint4*)(_bb + fo0);                          \
        const uint4 Rb = *(const uint4*)(_bb + fo1);                          \
        B16 ah, al, b0, b1, b2, b3;                                           \
        ah.u.x = pkh(Ra.x, Ra.y); ah.u.y = pkh(Ra.z, Ra.w);                   \
        ah.u.z = pkh(Rb.x, Rb.y); ah.u.w = pkh(Rb.z, Rb.w);                   \
        al.u.x = pkl(Ra.x, Ra.y); al.u.y = pkl(Ra.z, Ra.w);                   \
        al.u.z = pkl(Rb.x, Rb.y); al.u.w = pkl(Rb.z, Rb.w);                   \
        b0.u = WS0; b1.u = WS1; b2.u = WS2; b3.u = WS3;                       \
        acc0 = __builtin_amdgcn_mfma_f32_16x16x32_bf16(ah.v, b0.v, acc0, 0, 0, 0); \
        acc0 = __builtin_amdgcn_mfma_f32_16x16x32_bf16(ah.v, b1.v, acc0, 0, 0, 0); \
        acc0 = __builtin_amdgcn_mfma_f32_16x16x32_bf16(al.v, b0.v, acc0, 0, 0, 0); \
        acc1 = __builtin_amdgcn_mfma_f32_16x16x32_bf16(ah.v, b2.v, acc1, 0, 0, 0); \
        acc1 = __builtin_amdgcn_mfma_f32_16x16x32_bf16(ah.v, b3.v, acc1, 0, 0, 0); \
        acc1 = __builtin_amdgcn_mfma_f32_16x16x32_bf16(al.v, b2.v, acc1, 0, 0, 0); \
        ISSUE_W(WT0, WT1, WT2, WT3, (K) + 1);                                 \
        ISSUE_X((K) + 3);                                                     \
    } while (0)

    // prologue: stream order [x0, x1, W0, x2] = 10 outstanding
    ISSUE_X(0);
    ISSUE_X(1);
    ISSUE_W(A0, A1, A2, A3, 0);
    ISSUE_X(2);

    for (int k0 = 0; k0 < 64; k0 += 4) {
        BODY(k0 + 0, A0, A1, A2, A3, B0, B1, B2, B3);
        BODY(k0 + 1, B0, B1, B2, B3, A0, A1, A2, A3);
        BODY(k0 + 2, A0, A1, A2, A3, B0, B1, B2, B3);
        BODY(k0 + 3, B0, B1, B2, B3, A0, A1, A2, A3);
    }
    asm volatile("s_waitcnt vmcnt(0)" ::: "memory");   // drain tail dups
    __builtin_amdgcn_sched_barrier(0);

#undef BODY
#undef ISSUE_X
#undef ISSUE_W

    // ---- epilogue: scatter logits (C-map verified R7/R8/R11/R12) ----
#pragma unroll
    for (int rg = 0; rg < 4; ++rg) {
        const int row = tg * 16 + sA * 4 + rg;
        sc[row][eh * 32 + tA] = acc0[rg];
        sc[row][eh * 32 + 16 + tA] = acc1[rg];
    }
    __syncthreads();

    const float gbl = gb[lane];
    for (int tt = 8 * w; tt < 8 * w + 8; ++tt) {
        const float lg = sc[tt][lane];
        const float sg = 1.f / (1.f + expf(-lg));
        float cur = sg + gbl;

        float vals[7]; int idxs[7]; float us[7];
#pragma unroll
        for (int p = 0; p < 7; ++p) {
            float v = cur; int id = lane;
#pragma unroll
            for (int o = 32; o > 0; o >>= 1) {   // butterfly argmax, tie->low idx
                const float ov = __shfl_xor(v, o, 64);
                const int oid = __shfl_xor(id, o, 64);
                const bool take = (ov > v) || (ov == v && oid < id);
                v = take ? ov : v;
                id = take ? oid : id;
            }
            vals[p] = v; idxs[p] = id;
            us[p] = __shfl(sg, id, 64);
            if (lane == id) cur = -1e30f;
        }

        if (lane == 0) {
            const int t = tok0 + tt;
            bool flag = false;
#pragma unroll
            for (int p = 0; p < 6; ++p) flag = flag || (vals[p] - vals[p + 1] < THETA);
            float sum = 0.f;
#pragma unroll
            for (int p = 0; p < 6; ++p) sum += us[p];
#pragma unroll
            for (int p = 0; p < 6; ++p)
                out[(size_t)t * 6 + p] = us[p] / sum * 2.5f;
            float* oi = out + (size_t)M * 6 + (size_t)t * 8;
            oi[0] = 0.f; oi[1] = 1.f;
#pragma unroll
            for (int p = 0; p < 6; ++p) oi[2 + p] = (float)(idxs[p] + 2);
            if (flag) {
                const int pos = atomicAdd(wsc, 1);
                if (pos < MAXFLAG) wsc[1 + pos] = t;
            }
        }
    }
}

// ---------------------------------------------------------------------------
// Kernel 2: f64 refine of flagged tokens (exact ordering). Unchanged.
// ---------------------------------------------------------------------------
__launch_bounds__(256, 2)
__global__ void gate_refine(const float* __restrict__ x, const float* __restrict__ W,
                            const float* __restrict__ gb, float* __restrict__ out,
                            const int* __restrict__ wsc, int M) {
    __shared__ double lg[NEXP];
    int cnt = wsc[0];
    if (cnt > MAXFLAG) cnt = MAXFLAG;
    const int wv = threadIdx.x >> 6;
    const int lane = threadIdx.x & 63;

    for (int i = blockIdx.x; i < cnt; i += gridDim.x) {
        const int t = wsc[1 + i];
        const float* xr = x + (size_t)t * DDIM;
        for (int ee = 0; ee < 16; ++ee) {
            const int e = wv * 16 + ee;
            const float* wr = W + (size_t)e * DDIM;
            double a0 = 0, a1 = 0, a2 = 0, a3 = 0;
#pragma unroll
            for (int it = 0; it < DDIM / 256; ++it) {
                const float4 xv = *(const float4*)(xr + it * 256 + lane * 4);
                const float4 wvv = *(const float4*)(wr + it * 256 + lane * 4);
                a0 = fma((double)xv.x, (double)wvv.x, a0);
                a1 = fma((double)xv.y, (double)wvv.y, a1);
                a2 = fma((double)xv.z, (double)wvv.z, a2);
                a3 = fma((double)xv.w, (double)wvv.w, a3);
            }
            double sd = (a0 + a1) + (a2 + a3);
#pragma unroll
            for (int o = 32; o > 0; o >>= 1) sd += __shfl_down(sd, o, 64);
            if (lane == 0) lg[e] = sd;
        }
        __syncthreads();
        if (threadIdx.x < NEXP) {
            const double l = lg[threadIdx.x];
            lg[threadIdx.x] = 1.0 / (1.0 + exp(-l)) + (double)gb[threadIdx.x];
        }
        __syncthreads();
        if (threadIdx.x == 0) {
            double val[7]; int idx[7];
#pragma unroll
            for (int p = 0; p < 7; ++p) { val[p] = -1e30; idx[p] = 0; }
            for (int e = 0; e < NEXP; ++e) {
                double v = lg[e]; int id = e;
#pragma unroll
                for (int p = 0; p < 7; ++p) {
                    const bool gt = v > val[p];
                    const double ov = val[p]; const int oi2 = idx[p];
                    val[p] = gt ? v : ov; idx[p] = gt ? id : oi2;
                    v = gt ? ov : v;      id = gt ? oi2 : id;
                }
            }
            double s6[6], sum = 0.0;
#pragma unroll
            for (int p = 0; p < 6; ++p) { s6[p] = val[p] - (double)gb[idx[p]]; sum += s6[p]; }
#pragma unroll
            for (int p = 0; p < 6; ++p)
                out[(size_t)t * 6 + p] = (float)(s6[p] / sum * 2.5);
            float* oi = out + (size_t)M * 6 + (size_t)t * 8;
            oi[0] = 0.f; oi[1] = 1.f;
#pragma unroll
            for (int p = 0; p < 6; ++p) oi[2 + p] = (float)(idx[p] + 2);
        }
        __syncthreads();
    }
}

// ---------------------------------------------------------------------------
// Fallback: monolithic vector kernel (used only if ws too small)
// ---------------------------------------------------------------------------
__launch_bounds__(256, 2)
__global__ void gate_mono(const float* __restrict__ x, const float* __restrict__ W,
                          const float* __restrict__ gb, float* __restrict__ out,
                          int* __restrict__ wsc, int M) {
    __shared__ __align__(16) float xs[BK * BM];
    __shared__ __align__(16) float wsh[BK * NEXP];

    const int tid = threadIdx.x;
    const int tg = tid & 15;
    const int eg = tid >> 4;
    const int tok0 = blockIdx.x * BM;
    const int sr = tid >> 3;
    const int sq = tid & 7;
    const float* xsrc  = x + (size_t)(tok0 + sr) * DDIM + 4 * sq;
    const float* wsrc0 = W + (size_t)sr * DDIM + 4 * sq;
    const float* wsrc1 = W + (size_t)(sr + 32) * DDIM + 4 * sq;

    int xoff[16], woff[16];
#pragma unroll
    for (int c = 0; c < 16; ++c) {
        xoff[c] = c * (BM * 4) + 8 * (tg ^ c);
        woff[c] = c * (NEXP * 4) + 16 * (eg ^ c);
    }
    float acc[2][4];
#pragma unroll
    for (int i = 0; i < 2; ++i)
#pragma unroll
        for (int j = 0; j < 4; ++j) acc[i][j] = 0.f;

    float4 px0 = *(const float4*)(xsrc);
    float4 px1 = *(const float4*)(xsrc + 32);
    float4 pw00 = *(const float4*)(wsrc0);
    float4 pw01 = *(const float4*)(wsrc0 + 32);
    float4 pw10 = *(const float4*)(wsrc1);
    float4 pw11 = *(const float4*)(wsrc1 + 32);

    for (int ch = 0; ch < DDIM / BK; ++ch) {
        __syncthreads();
#pragma unroll
        for (int m = 0; m < 4; ++m) {
            const int kkA = 4 * sq + m;
            const int kkB = kkA + 32;
            xs[kkA * BM + ((sr & 1) + 2 * ((sr >> 1) ^ (kkA & 15)))] = ((const float*)&px0)[m];
            xs[kkB * BM + ((sr & 1) + 2 * ((sr >> 1) ^ (kkB & 15)))] = ((const float*)&px1)[m];
            wsh[kkA * NEXP + ((sr & 3) + 4 * ((sr >> 2) ^ (kkA & 15)))] = ((const float*)&pw00)[m];
            wsh[kkB * NEXP + ((sr & 3) + 4 * ((sr >> 2) ^ (kkB & 15)))] = ((const float*)&pw01)[m];
            wsh[kkA * NEXP + (((sr + 32) & 3) + 4 * (((sr + 32) >> 2) ^ (kkA & 15)))] = ((const float*)&pw10)[m];
            wsh[kkB * NEXP + (((sr + 32) & 3) + 4 * (((sr + 32) >> 2) ^ (kkB & 15)))] = ((const float*)&pw11)[m];
        }
        __syncthreads();
        if (ch + 1 < DDIM / BK) {
            const int k0 = (ch + 1) * BK;
            px0 = *(const float4*)(xsrc + k0);
            px1 = *(const float4*)(xsrc + k0 + 32);
            pw00 = *(const float4*)(wsrc0 + k0);
            pw01 = *(const float4*)(wsrc0 + k0 + 32);
            pw10 = *(const float4*)(wsrc1 + k0);
            pw11 = *(const float4*)(wsrc1 + k0 + 32);
        }
        const char* xb = (const char*)xs;
        const char* wb = (const char*)wsh;
#pragma unroll
        for (int rep = 0; rep < 4; ++rep) {
#pragma unroll
            for (int c = 0; c < 16; ++c) {
                const float2 xv = *(const float2*)(xb + rep * (16 * BM * 4) + xoff[c]);
                const float4 wv = *(const float4*)(wb + rep * (16 * NEXP * 4) + woff[c]);
                acc[0][0] = fmaf(xv.x, wv.x, acc[0][0]);
                acc[0][1] = fmaf(xv.x, wv.y, acc[0][1]);
                acc[0][2] = fmaf(xv.x, wv.z, acc[0][2]);
                acc[0][3] = fmaf(xv.x, wv.w, acc[0][3]);
                acc[1][0] = fmaf(xv.y, wv.x, acc[1][0]);
                acc[1][1] = fmaf(xv.y, wv.y, acc[1][1]);
                acc[1][2] = fmaf(xv.y, wv.z, acc[1][2]);
                acc[1][3] = fmaf(xv.y, wv.w, acc[1][3]);
            }
        }
    }

    __syncthreads();
    float* sc = wsh;
#pragma unroll
    for (int i = 0; i < 2; ++i)
#pragma unroll
        for (int j = 0; j < 4; ++j)
            sc[(2 * tg + i) * 68 + (4 * eg + j)] = acc[i][j];
    __syncthreads();

    if (tid < BM) {
        const int t = tok0 + tid;
        float val[7]; int idx[7];
#pragma unroll
        for (int p = 0; p < 7; ++p) { val[p] = -1e30f; idx[p] = 0; }
        for (int e = 0; e < NEXP; ++e) {
            const float l = sc[tid * 68 + e];
            const float sg = 1.f / (1.f + expf(-l));
            float v = sg + gb[e];
            int id = e;
#pragma unroll
            for (int p = 0; p < 7; ++p) {
                const bool gt = v > val[p];
                const float ov = val[p]; const int oi = idx[p];
                val[p] = gt ? v : ov;  idx[p] = gt ? id : oi;
                v = gt ? ov : v;       id = gt ? oi : id;
            }
        }
        bool flag = false;
#pragma unroll
        for (int p = 0; p < 6; ++p) flag = flag || (val[p] - val[p + 1] < THETA);

        float s6[6]; float sum = 0.f;
#pragma unroll
        for (int p = 0; p < 6; ++p) {
            const float l = sc[tid * 68 + idx[p]];
            s6[p] = 1.f / (1.f + expf(-l));
            sum += s6[p];
        }
#pragma unroll
        for (int p = 0; p < 6; ++p)
            out[(size_t)t * 6 + p] = s6[p] / sum * 2.5f;

        float* oi = out + (size_t)M * 6 + (size_t)t * 8;
        oi[0] = 0.f; oi[1] = 1.f;
#pragma unroll
        for (int p = 0; p < 6; ++p) oi[2 + p] = (float)(idx[p] + 2);

        if (flag && wsc) {
            const int pos = atomicAdd(wsc, 1);
            if (pos < MAXFLAG) wsc[1 + pos] = t;
        }
    }
}

extern "C" void kernel_launch(void* const* d_in, const int* in_sizes, int n_in,
                              void* d_out, int out_size, void* d_ws, size_t ws_size,
                              hipStream_t stream) {
    const float* x = (const float*)d_in[0];
    const float* W = (const float*)d_in[1];
    const float* gb = (const float*)d_in[2];
    float* out = (float*)d_out;
    const int M = in_sizes[0] / DDIM;   // 16384

    // ws layout: [flags 64KB | Wp 512KB]
    const size_t need = (size_t)FLAGREGION + (size_t)WPACKB;

    if (ws_size >= need && (M % 32) == 0) {
        int* wsc = (int*)d_ws;
        ushort* Wp = (ushort*)((char*)d_ws + FLAGREGION);
        hipMemsetAsync(d_ws, 0, sizeof(int), stream);
        hipLaunchKernelGGL(w_pack, dim3(64), dim3(256), 0, stream, W, Wp);
        hipLaunchKernelGGL(gate_main, dim3(M / 32), dim3(256), 0, stream,
                           x, Wp, gb, out, wsc, M);
        hipLaunchKernelGGL(gate_refine, dim3(256), dim3(256), 0, stream,
                           x, W, gb, out, wsc, M);
    } else {
        const bool refine_ok = ws_size >= (size_t)(1 + MAXFLAG) * sizeof(int);
        int* wsc = refine_ok ? (int*)d_ws : (int*)nullptr;
        if (refine_ok) hipMemsetAsync(d_ws, 0, sizeof(int), stream);
        hipLaunchKernelGGL(gate_mono, dim3(M / BM), dim3(256), 0, stream,
                           x, W, gb, out, wsc, M);
        if (refine_ok)
            hipLaunchKernelGGL(gate_refine, dim3(256), dim3(256), 0, stream,
                               x, W, gb, out, wsc, M);
    }
}

// Round 14
// 114.149 us; speedup vs baseline: 1.3125x; 1.0840x over previous
//
#include <hip/hip_runtime.h>
#include <math.h>

#define DDIM 2048
#define NEXP 64
#define BM 32            // (mono fallback tile)
#define BK 64
#define THETA 3e-5f
#define MAXFLAG 16383
#define FLAGREGION 65536
#define WPACKB (64 * 4 * 2 * 1024)   // 512 KB packed W frags

typedef __attribute__((ext_vector_type(8))) short bf16x8;
typedef __attribute__((ext_vector_type(4))) float f32x4;

union B16 { uint4 u; bf16x8 v; };

// RNE f32->bf16 pair pack (offline W split)
__device__ inline unsigned pkbf(float a, float b, float& fa, float& fb) {
    unsigned ba = __float_as_uint(a), bb = __float_as_uint(b);
    unsigned ra = (ba + 0x7fffu + ((ba >> 16) & 1u)) & 0xffff0000u;
    unsigned rb = (bb + 0x7fffu + ((bb >> 16) & 1u)) & 0xffff0000u;
    fa = __uint_as_float(ra); fb = __uint_as_float(rb);
    return (ra >> 16) | rb;
}

// trunc-pack: dst = [bf16t(b) | bf16t(a)] via one v_perm
__device__ inline unsigned pkh(unsigned a, unsigned b) {
    return __builtin_amdgcn_perm(b, a, 0x07060302u);
}
// low-part pack: xl = x - trunc16(x), trunc-packed
__device__ inline unsigned pkl(unsigned a, unsigned b) {
    const float fa = __uint_as_float(a) - __uint_as_float(a & 0xffff0000u);
    const float fb = __uint_as_float(b) - __uint_as_float(b & 0xffff0000u);
    return pkh(__float_as_uint(fa), __float_as_uint(fb));
}

// ---------------------------------------------------------------------------
// Kernel 0: pack W[64][2048] f32 into MFMA B-fragment order, RNE bf16 split.
// Wp byte layout: ((ks*4 + et)*2 + hl)*1024 + lane*16. 512 KB, L2-resident.
// ---------------------------------------------------------------------------
__global__ void w_pack(const float* __restrict__ W, ushort* __restrict__ Wp) {
    const int gid = blockIdx.x * 256 + threadIdx.x;   // 16384 = 64ks*4et*64ln
    const int ln = gid & 63, et = (gid >> 6) & 3, ks = gid >> 8;
    const float* src = W + (size_t)(et * 16 + (ln & 15)) * DDIM + 32 * ks + 8 * (ln >> 4);
    const float4 f0 = *(const float4*)(src);
    const float4 f1 = *(const float4*)(src + 4);
    uint4 H, L; float h0, h1, h2, h3, h4, h5, h6, h7, d;
    H.x = pkbf(f0.x, f0.y, h0, h1);
    H.y = pkbf(f0.z, f0.w, h2, h3);
    H.z = pkbf(f1.x, f1.y, h4, h5);
    H.w = pkbf(f1.z, f1.w, h6, h7);
    L.x = pkbf(f0.x - h0, f0.y - h1, d, d);
    L.y = pkbf(f0.z - h2, f0.w - h3, d, d);
    L.z = pkbf(f1.x - h4, f1.y - h5, d, d);
    L.w = pkbf(f1.z - h6, f1.w - h7, d, d);
    const size_t hb = ((size_t)(ks * 4 + et) * 2 + 0) * 512 + ln * 8;  // ushort units
    const size_t lb = ((size_t)(ks * 4 + et) * 2 + 1) * 512 + ln * 8;
    *(uint4*)(Wp + hb) = H;
    *(uint4*)(Wp + lb) = L;
}

// ---------------------------------------------------------------------------
// Kernel 1: coalesced-gll streaming MFMA gate, 3-BODY-DEEP on BOTH streams.
// Block = 16 tokens x 4 waves; wave wu = 16 tokens x experts [16wu,16wu+16)
// (1 tile, 3 MFMA/body). Grid 1024 = 4 blk/CU = 4 waves/SIMD.
// Per body: 2 W asm loads (coalesced 1KB, Wp) + 2 x global_load_lds
// (contiguous 128B/row, source pre-swizzled) into per-wave 4-slot LDS ring.
// Schedule (derived, uniform): prologue [W0][W1,x0][W2,x1][W3,x2]=14 out;
// body k: s_waitcnt vmcnt(8) retires {...,x(k)} (W(k),x(k) both issued 3
// bodies earlier); issue [W(k+4)->same set, x(k+3)->slot]. Hiding budget
// 3 bodies x ~50cyc x 4 waves/SIMD ~ 600cyc > L2/L3 latency.
// R13 bug fixed: its issue order gave W a ONE-body retire distance ->
// per-body W-latency stall at 2 waves/SIMD.
// ---------------------------------------------------------------------------
__launch_bounds__(256, 2)
__global__ void gate_main(const float* __restrict__ x, const ushort* __restrict__ Wp,
                          const float* __restrict__ gb, float* __restrict__ out,
                          int* __restrict__ wsc, int M) {
    __shared__ __align__(16) char stage[4][8192];   // per-wave 4x2KB ring
    __shared__ float sc[16][NEXP + 4];              // 4.3 KB logit table

    const int tid = threadIdx.x;
    const int lane = tid & 63;
    const int w = tid >> 6;
    const int wu = __builtin_amdgcn_readfirstlane(w);
    const int tok0 = blockIdx.x * 16;

    // x gll source (per lane, 2 instrs): instr i covers rows 8i..8i+7.
    // LDS slot u (16B) of row t holds source chunk u ^ (t&7).
    const int lr = lane >> 3;
    const int uc = (lane & 7) ^ lr;
    const float* gp0 = x + (size_t)(tok0 + lr) * DDIM + uc * 4;
    const float* gp1 = x + (size_t)(tok0 + 8 + lr) * DDIM + uc * 4;

    // frag-read offsets (match store swizzle): t=lane&15, s=lane>>4, m=t&7
    const int tA = lane & 15, sA = lane >> 4, mA = tA & 7;
    const int fo0 = tA * 128 + (((2 * sA) ^ mA) << 4);
    const int fo1 = tA * 128 + (((2 * sA + 1) ^ mA) << 4);
    const char* mybase = &stage[wu][0];

    // W: wave wu covers experts [16wu,16wu+16) -> et = wu
    const unsigned wofs = (unsigned)(lane * 16 + wu * 2048);
    const ushort* wbase = Wp;   // SGPR base

    f32x4 acc = (f32x4){0.f, 0.f, 0.f, 0.f};

    uint4 W0h, W0l, W1h, W1l, W2h, W2l, W3h, W3l;   // 4 sets x {bh,bl}

#define ISSUE_W(WH, WL, KST)                                                  \
    do {                                                                      \
        const int _kc = (KST) > 63 ? 63 : (KST);                              \
        const unsigned _ow = wofs + (unsigned)_kc * 8192u;                    \
        asm volatile("global_load_dwordx4 %0, %1, %2 offset:0"                \
                     : "=&v"(WH) : "v"(_ow), "s"(wbase));                     \
        asm volatile("global_load_dwordx4 %0, %1, %2 offset:1024"             \
                     : "=&v"(WL) : "v"(_ow), "s"(wbase));                     \
    } while (0)

#define ISSUE_X(KST)                                                          \
    do {                                                                      \
        const int _kc = (KST) > 63 ? 63 : (KST);                              \
        char* _d = &stage[wu][((KST) & 3) * 2048];                            \
        __builtin_amdgcn_global_load_lds((const unsigned*)(gp0 + _kc * 32),   \
                                         (unsigned*)_d, 16, 0, 0);            \
        __builtin_amdgcn_global_load_lds((const unsigned*)(gp1 + _kc * 32),   \
                                         (unsigned*)(_d + 1024), 16, 0, 0);   \
    } while (0)

#define BODY(K, WH, WL)                                                       \
    do {                                                                      \
        asm volatile("s_waitcnt vmcnt(8)" ::: "memory");                      \
        __builtin_amdgcn_sched_barrier(0);                                    \
        const char* _bb = mybase + ((K) & 3) * 2048;                          \
        const uint4 Ra = *(const uint4*)(_bb + fo0);                          \
        const uint4 Rb = *(const uint4*)(_bb + fo1);                          \
        B16 ah, al, bh, bl;                                                   \
        ah.u.x = pkh(Ra.x, Ra.y); ah.u.y = pkh(Ra.z, Ra.w);                   \
        ah.u.z = pkh(Rb.x, Rb.y); ah.u.w = pkh(Rb.z, Rb.w);                   \
        al.u.x = pkl(Ra.x, Ra.y); al.u.y = pkl(Ra.z, Ra.w);                   \
        al.u.z = pkl(Rb.x, Rb.y); al.u.w = pkl(Rb.z, Rb.w);                   \
        bh.u = WH; bl.u = WL;                                                 \
        acc = __builtin_amdgcn_mfma_f32_16x16x32_bf16(ah.v, bh.v, acc, 0, 0, 0); \
        acc = __builtin_amdgcn_mfma_f32_16x16x32_bf16(ah.v, bl.v, acc, 0, 0, 0); \
        acc = __builtin_amdgcn_mfma_f32_16x16x32_bf16(al.v, bh.v, acc, 0, 0, 0); \
        ISSUE_W(WH, WL, (K) + 4);                                             \
        ISSUE_X((K) + 3);                                                     \
    } while (0)

    // prologue: [W0][W1,x0][W2,x1][W3,x2] = 14 outstanding
    ISSUE_W(W0h, W0l, 0);
    ISSUE_W(W1h, W1l, 1); ISSUE_X(0);
    ISSUE_W(W2h, W2l, 2); ISSUE_X(1);
    ISSUE_W(W3h, W3l, 3); ISSUE_X(2);

    for (int k0 = 0; k0 < 64; k0 += 4) {
        BODY(k0 + 0, W0h, W0l);
        BODY(k0 + 1, W1h, W1l);
        BODY(k0 + 2, W2h, W2l);
        BODY(k0 + 3, W3h, W3l);
    }
    asm volatile("s_waitcnt vmcnt(0)" ::: "memory");   // drain tail dups
    __builtin_amdgcn_sched_barrier(0);

#undef BODY
#undef ISSUE_X
#undef ISSUE_W

    // ---- epilogue: scatter logits (C-map verified R7/R8/R11-R13) ----
#pragma unroll
    for (int rg = 0; rg < 4; ++rg)
        sc[sA * 4 + rg][16 * wu + tA] = acc[rg];
    __syncthreads();

    const float gbl = gb[lane];
    for (int tt = 4 * w; tt < 4 * w + 4; ++tt) {
        const float lg = sc[tt][lane];
        const float sg = 1.f / (1.f + expf(-lg));
        float cur = sg + gbl;

        float vals[7]; int idxs[7]; float us[7];
#pragma unroll
        for (int p = 0; p < 7; ++p) {
            float v = cur; int id = lane;
#pragma unroll
            for (int o = 32; o > 0; o >>= 1) {   // butterfly argmax, tie->low idx
                const float ov = __shfl_xor(v, o, 64);
                const int oid = __shfl_xor(id, o, 64);
                const bool take = (ov > v) || (ov == v && oid < id);
                v = take ? ov : v;
                id = take ? oid : id;
            }
            vals[p] = v; idxs[p] = id;
            us[p] = __shfl(sg, id, 64);
            if (lane == id) cur = -1e30f;
        }

        if (lane == 0) {
            const int t = tok0 + tt;
            bool flag = false;
#pragma unroll
            for (int p = 0; p < 6; ++p) flag = flag || (vals[p] - vals[p + 1] < THETA);
            float sum = 0.f;
#pragma unroll
            for (int p = 0; p < 6; ++p) sum += us[p];
#pragma unroll
            for (int p = 0; p < 6; ++p)
                out[(size_t)t * 6 + p] = us[p] / sum * 2.5f;
            float* oi = out + (size_t)M * 6 + (size_t)t * 8;
            oi[0] = 0.f; oi[1] = 1.f;
#pragma unroll
            for (int p = 0; p < 6; ++p) oi[2 + p] = (float)(idxs[p] + 2);
            if (flag) {
                const int pos = atomicAdd(wsc, 1);
                if (pos < MAXFLAG) wsc[1 + pos] = t;
            }
        }
    }
}

// ---------------------------------------------------------------------------
// Kernel 2: f64 refine of flagged tokens (exact ordering). Unchanged.
// ---------------------------------------------------------------------------
__launch_bounds__(256, 2)
__global__ void gate_refine(const float* __restrict__ x, const float* __restrict__ W,
                            const float* __restrict__ gb, float* __restrict__ out,
                            const int* __restrict__ wsc, int M) {
    __shared__ double lg[NEXP];
    int cnt = wsc[0];
    if (cnt > MAXFLAG) cnt = MAXFLAG;
    const int wv = threadIdx.x >> 6;
    const int lane = threadIdx.x & 63;

    for (int i = blockIdx.x; i < cnt; i += gridDim.x) {
        const int t = wsc[1 + i];
        const float* xr = x + (size_t)t * DDIM;
        for (int ee = 0; ee < 16; ++ee) {
            const int e = wv * 16 + ee;
            const float* wr = W + (size_t)e * DDIM;
            double a0 = 0, a1 = 0, a2 = 0, a3 = 0;
#pragma unroll
            for (int it = 0; it < DDIM / 256; ++it) {
                const float4 xv = *(const float4*)(xr + it * 256 + lane * 4);
                const float4 wvv = *(const float4*)(wr + it * 256 + lane * 4);
                a0 = fma((double)xv.x, (double)wvv.x, a0);
                a1 = fma((double)xv.y, (double)wvv.y, a1);
                a2 = fma((double)xv.z, (double)wvv.z, a2);
                a3 = fma((double)xv.w, (double)wvv.w, a3);
            }
            double sd = (a0 + a1) + (a2 + a3);
#pragma unroll
            for (int o = 32; o > 0; o >>= 1) sd += __shfl_down(sd, o, 64);
            if (lane == 0) lg[e] = sd;
        }
        __syncthreads();
        if (threadIdx.x < NEXP) {
            const double l = lg[threadIdx.x];
            lg[threadIdx.x] = 1.0 / (1.0 + exp(-l)) + (double)gb[threadIdx.x];
        }
        __syncthreads();
        if (threadIdx.x == 0) {
            double val[7]; int idx[7];
#pragma unroll
            for (int p = 0; p < 7; ++p) { val[p] = -1e30; idx[p] = 0; }
            for (int e = 0; e < NEXP; ++e) {
                double v = lg[e]; int id = e;
#pragma unroll
                for (int p = 0; p < 7; ++p) {
                    const bool gt = v > val[p];
                    const double ov = val[p]; const int oi2 = idx[p];
                    val[p] = gt ? v : ov; idx[p] = gt ? id : oi2;
                    v = gt ? ov : v;      id = gt ? oi2 : id;
                }
            }
            double s6[6], sum = 0.0;
#pragma unroll
            for (int p = 0; p < 6; ++p) { s6[p] = val[p] - (double)gb[idx[p]]; sum += s6[p]; }
#pragma unroll
            for (int p = 0; p < 6; ++p)
                out[(size_t)t * 6 + p] = (float)(s6[p] / sum * 2.5);
            float* oi = out + (size_t)M * 6 + (size_t)t * 8;
            oi[0] = 0.f; oi[1] = 1.f;
#pragma unroll
            for (int p = 0; p < 6; ++p) oi[2 + p] = (float)(idx[p] + 2);
        }
        __syncthreads();
    }
}

// ---------------------------------------------------------------------------
// Fallback: monolithic vector kernel (used only if ws too small)
// ---------------------------------------------------------------------------
__launch_bounds__(256, 2)
__global__ void gate_mono(const float* __restrict__ x, const float* __restrict__ W,
                          const float* __restrict__ gb, float* __restrict__ out,
                          int* __restrict__ wsc, int M) {
    __shared__ __align__(16) float xs[BK * BM];
    __shared__ __align__(16) float wsh[BK * NEXP];

    const int tid = threadIdx.x;
    const int tg = tid & 15;
    const int eg = tid >> 4;
    const int tok0 = blockIdx.x * BM;
    const int sr = tid >> 3;
    const int sq = tid & 7;
    const float* xsrc  = x + (size_t)(tok0 + sr) * DDIM + 4 * sq;
    const float* wsrc0 = W + (size_t)sr * DDIM + 4 * sq;
    const float* wsrc1 = W + (size_t)(sr + 32) * DDIM + 4 * sq;

    int xoff[16], woff[16];
#pragma unroll
    for (int c = 0; c < 16; ++c) {
        xoff[c] = c * (BM * 4) + 8 * (tg ^ c);
        woff[c] = c * (NEXP * 4) + 16 * (eg ^ c);
    }
    float acc[2][4];
#pragma unroll
    for (int i = 0; i < 2; ++i)
#pragma unroll
        for (int j = 0; j < 4; ++j) acc[i][j] = 0.f;

    float4 px0 = *(const float4*)(xsrc);
    float4 px1 = *(const float4*)(xsrc + 32);
    float4 pw00 = *(const float4*)(wsrc0);
    float4 pw01 = *(const float4*)(wsrc0 + 32);
    float4 pw10 = *(const float4*)(wsrc1);
    float4 pw11 = *(const float4*)(wsrc1 + 32);

    for (int ch = 0; ch < DDIM / BK; ++ch) {
        __syncthreads();
#pragma unroll
        for (int m = 0; m < 4; ++m) {
            const int kkA = 4 * sq + m;
            const int kkB = kkA + 32;
            xs[kkA * BM + ((sr & 1) + 2 * ((sr >> 1) ^ (kkA & 15)))] = ((const float*)&px0)[m];
            xs[kkB * BM + ((sr & 1) + 2 * ((sr >> 1) ^ (kkB & 15)))] = ((const float*)&px1)[m];
            wsh[kkA * NEXP + ((sr & 3) + 4 * ((sr >> 2) ^ (kkA & 15)))] = ((const float*)&pw00)[m];
            wsh[kkB * NEXP + ((sr & 3) + 4 * ((sr >> 2) ^ (kkB & 15)))] = ((const float*)&pw01)[m];
            wsh[kkA * NEXP + (((sr + 32) & 3) + 4 * (((sr + 32) >> 2) ^ (kkA & 15)))] = ((const float*)&pw10)[m];
            wsh[kkB * NEXP + (((sr + 32) & 3) + 4 * (((sr + 32) >> 2) ^ (kkB & 15)))] = ((const float*)&pw11)[m];
        }
        __syncthreads();
        if (ch + 1 < DDIM / BK) {
            const int k0 = (ch + 1) * BK;
            px0 = *(const float4*)(xsrc + k0);
            px1 = *(const float4*)(xsrc + k0 + 32);
            pw00 = *(const float4*)(wsrc0 + k0);
            pw01 = *(const float4*)(wsrc0 + k0 + 32);
            pw10 = *(const float4*)(wsrc1 + k0);
            pw11 = *(const float4*)(wsrc1 + k0 + 32);
        }
        const char* xb = (const char*)xs;
        const char* wb = (const char*)wsh;
#pragma unroll
        for (int rep = 0; rep < 4; ++rep) {
#pragma unroll
            for (int c = 0; c < 16; ++c) {
                const float2 xv = *(const float2*)(xb + rep * (16 * BM * 4) + xoff[c]);
                const float4 wv = *(const float4*)(wb + rep * (16 * NEXP * 4) + woff[c]);
                acc[0][0] = fmaf(xv.x, wv.x, acc[0][0]);
                acc[0][1] = fmaf(xv.x, wv.y, acc[0][1]);
                acc[0][2] = fmaf(xv.x, wv.z, acc[0][2]);
                acc[0][3] = fmaf(xv.x, wv.w, acc[0][3]);
                acc[1][0] = fmaf(xv.y, wv.x, acc[1][0]);
                acc[1][1] = fmaf(xv.y, wv.y, acc[1][1]);
                acc[1][2] = fmaf(xv.y, wv.z, acc[1][2]);
                acc[1][3] = fmaf(xv.y, wv.w, acc[1][3]);
            }
        }
    }

    __syncthreads();
    float* sc = wsh;
#pragma unroll
    for (int i = 0; i < 2; ++i)
#pragma unroll
        for (int j = 0; j < 4; ++j)
            sc[(2 * tg + i) * 68 + (4 * eg + j)] = acc[i][j];
    __syncthreads();

    if (tid < BM) {
        const int t = tok0 + tid;
        float val[7]; int idx[7];
#pragma unroll
        for (int p = 0; p < 7; ++p) { val[p] = -1e30f; idx[p] = 0; }
        for (int e = 0; e < NEXP; ++e) {
            const float l = sc[tid * 68 + e];
            const float sg = 1.f / (1.f + expf(-l));
            float v = sg + gb[e];
            int id = e;
#pragma unroll
            for (int p = 0; p < 7; ++p) {
                const bool gt = v > val[p];
                const float ov = val[p]; const int oi = idx[p];
                val[p] = gt ? v : ov;  idx[p] = gt ? id : oi;
                v = gt ? ov : v;       id = gt ? oi : id;
            }
        }
        bool flag = false;
#pragma unroll
        for (int p = 0; p < 6; ++p) flag = flag || (val[p] - val[p + 1] < THETA);

        float s6[6]; float sum = 0.f;
#pragma unroll
        for (int p = 0; p < 6; ++p) {
            const float l = sc[tid * 68 + idx[p]];
            s6[p] = 1.f / (1.f + expf(-l));
            sum += s6[p];
        }
#pragma unroll
        for (int p = 0; p < 6; ++p)
            out[(size_t)t * 6 + p] = s6[p] / sum * 2.5f;

        float* oi = out + (size_t)M * 6 + (size_t)t * 8;
        oi[0] = 0.f; oi[1] = 1.f;
#pragma unroll
        for (int p = 0; p < 6; ++p) oi[2 + p] = (float)(idx[p] + 2);

        if (flag && wsc) {
            const int pos = atomicAdd(wsc, 1);
            if (pos < MAXFLAG) wsc[1 + pos] = t;
        }
    }
}

extern "C" void kernel_launch(void* const* d_in, const int* in_sizes, int n_in,
                              void* d_out, int out_size, void* d_ws, size_t ws_size,
                              hipStream_t stream) {
    const float* x = (const float*)d_in[0];
    const float* W = (const float*)d_in[1];
    const float* gb = (const float*)d_in[2];
    float* out = (float*)d_out;
    const int M = in_sizes[0] / DDIM;   // 16384

    // ws layout: [flags 64KB | Wp 512KB]
    const size_t need = (size_t)FLAGREGION + (size_t)WPACKB;

    if (ws_size >= need && (M % 16) == 0) {
        int* wsc = (int*)d_ws;
        ushort* Wp = (ushort*)((char*)d_ws + FLAGREGION);
        hipMemsetAsync(d_ws, 0, sizeof(int), stream);
        hipLaunchKernelGGL(w_pack, dim3(64), dim3(256), 0, stream, W, Wp);
        hipLaunchKernelGGL(gate_main, dim3(M / 16), dim3(256), 0, stream,
                           x, Wp, gb, out, wsc, M);
        hipLaunchKernelGGL(gate_refine, dim3(256), dim3(256), 0, stream,
                           x, W, gb, out, wsc, M);
    } else {
        const bool refine_ok = ws_size >= (size_t)(1 + MAXFLAG) * sizeof(int);
        int* wsc = refine_ok ? (int*)d_ws : (int*)nullptr;
        if (refine_ok) hipMemsetAsync(d_ws, 0, sizeof(int), stream);
        hipLaunchKernelGGL(gate_mono, dim3(M / BM), dim3(256), 0, stream,
                           x, W, gb, out, wsc, M);
        if (refine_ok)
            hipLaunchKernelGGL(gate_refine, dim3(256), dim3(256), 0, stream,
                               x, W, gb, out, wsc, M);
    }
}